// Round 19
// baseline (163.070 us; speedup 1.0000x reference)
//
#include <hip/hip_runtime.h>
#include <hip/hip_bf16.h>

#define C_ 256
#define N_ 4096
#define NH_ 8

typedef unsigned short u16;
typedef unsigned int u32;
typedef __attribute__((ext_vector_type(8))) short s8v;
typedef __attribute__((ext_vector_type(4))) float f4v;

#define MFMA16 __builtin_amdgcn_mfma_f32_16x16x32_bf16

__device__ __forceinline__ float bf2f(u16 b){ union{u32 u; float f;} v; v.u=((u32)b)<<16; return v.f; }
__device__ __forceinline__ u16 f2bf(float f){
  __hip_bfloat16 h = __float2bfloat16(f);
  u16 u; __builtin_memcpy(&u, &h, 2); return u;
}

__device__ __forceinline__ void gl_lds16(const u16* g, u16* l){
  __builtin_amdgcn_global_load_lds((const __attribute__((address_space(1))) u32*)g,
                                   (__attribute__((address_space(3))) u32*)l, 16, 0, 0);
}

// ---------------- kernel A1: pixel rnorm + write xnT[b][n][c] bf16 ----------------
__global__ __launch_bounds__(256) void k_prep(const float* __restrict__ x, const float* __restrict__ nw,
                                              u16* __restrict__ xnT){
  __shared__ float red[256];
  __shared__ float nws[256];
  const int tid = threadIdx.x;
  nws[tid] = nw[tid];
  const int blk = blockIdx.x, b = blk>>6, n0 = (blk&63)*64;
  const int cq = tid>>6, px = tid&63;
  const float* xp = x + (size_t)b*(C_*N_) + (size_t)(cq*64)*N_ + n0 + px;
  float v[64]; float s = 0.f;
  #pragma unroll
  for (int i=0;i<64;i++){ float t = xp[(size_t)i*N_]; v[i]=t; s = fmaf(t,t,s); }
  red[tid] = s;
  __syncthreads();
  const float st = red[px] + red[64+px] + red[128+px] + red[192+px];
  const float r = 16.0f / fmaxf(sqrtf(st), 1e-12f);
  u16* o = xnT + ((size_t)b*4096 + n0 + px)*256 + cq*64;
  #pragma unroll
  for (int i=0;i<64;i+=2){
    *(u32*)(o+i) = (u32)f2bf(v[i]*r*nws[cq*64+i]) | ((u32)f2bf(v[i+1]*r*nws[cq*64+i+1])<<16);
  }
}

// ---------------- kernel A2: weights -> bf16 (float4 vectorized) ----------------
__global__ __launch_bounds__(256) void k_wconv(const float* __restrict__ qkvw, const float* __restrict__ ow,
                                               u16* __restrict__ wqkv, u16* __restrict__ owb){
  int q = blockIdx.x*256 + threadIdx.x;   // 131072 quads (524288 elements)
  int i = q*4;
  const float4 f4 = (i < 393216) ? *(const float4*)&qkvw[i] : *(const float4*)&ow[i-393216];
  u32 lo = (u32)f2bf(f4.x) | ((u32)f2bf(f4.y)<<16);
  u32 hi = (u32)f2bf(f4.z) | ((u32)f2bf(f4.w)<<16);
  u16* dst = (i < 393216) ? (wqkv + i) : (owb + (i-393216));
  *(u32*)dst = lo;
  *(u32*)(dst+2) = hi;
}

// ---------------- kernel B: LDS-staged K/V GEMM + fixed-M softmax (R13 proven) ----------
__global__ __launch_bounds__(256,3) void k_kv(const u16* __restrict__ xnT, const u16* __restrict__ wqkv,
    u16* __restrict__ ctxp, float* __restrict__ Mp, float* __restrict__ Sp){
  __shared__ u16 xs[64*256];     // 32KB staged x tile (swizzled)
  __shared__ u16 pbuf[64*72];
  __shared__ u16 vbuf[64*72];
  const int idx = blockIdx.x;
  const int ch = idx&7, h = (idx>>3)&7, b = idx>>6;
  const int tid=threadIdx.x, w=tid>>6, l=tid&63, l15=l&15, lg=l>>4;
  const int swl = (l15&7)<<4;
  const u16* xb  = xnT + (size_t)b*(4096*256);
  const int srow = (l>>5);
  const int scolB = (l&31)*16;
  s8v ak[8], av[8];
  {
    const u16* wkp = wqkv + (size_t)(512 + h*64 + w*16 + l15)*256 + lg*8;
    #pragma unroll
    for (int cs=0; cs<8; cs++){ ak[cs] = *(const s8v*)(wkp + cs*32); av[cs] = *(const s8v*)(wkp + 131072 + cs*32); }
  }
  int colOff[8];
  #pragma unroll
  for (int cs=0; cs<8; cs++) colOff[cs] = (((cs<<6)+(lg<<4)) ^ swl)>>1;

  f4v acc[4];
  #pragma unroll
  for (int et=0;et<4;et++) acc[et] = (f4v){0.f,0.f,0.f,0.f};
  float ps[4] = {0.f,0.f,0.f,0.f};

  {
    const int n0 = ch*512;
    #pragma unroll
    for (int i=0;i<8;i++){
      int rloc = w*16 + i*2 + srow;
      int scol = scolB ^ ((rloc&7)<<4);
      gl_lds16(xb + (size_t)(n0+rloc)*256 + (scol>>1), &xs[(w*16+i*2)*256]);
    }
  }

  for (int t=0; t<8; ++t){
    __syncthreads();
    f4v kacc[4], vacc[4];
    #pragma unroll
    for (int ns=0;ns<4;ns++){ kacc[ns]=(f4v){0.f,0.f,0.f,0.f}; vacc[ns]=(f4v){0.f,0.f,0.f,0.f}; }
    #pragma unroll
    for (int cs=0; cs<8; cs++){
      #pragma unroll
      for (int ns=0; ns<4; ns++){
        s8v bfr = *(const s8v*)&xs[(ns*16+l15)*256 + colOff[cs]];
        kacc[ns] = MFMA16(ak[cs], bfr, kacc[ns], 0,0,0);
        vacc[ns] = MFMA16(av[cs], bfr, vacc[ns], 0,0,0);
      }
    }
    #pragma unroll
    for (int j=0;j<4;j++){
      const int row = w*16 + lg*4 + j;
      #pragma unroll
      for (int ns=0;ns<4;ns++){
        float e = __expf(kacc[ns][j] - 30.0f);
        ps[j] += e;
        pbuf[row*72 + ns*16+l15] = f2bf(e);
        vbuf[row*72 + ns*16+l15] = f2bf(vacc[ns][j]);
      }
    }
    __syncthreads();
    if (t<7){
      const int n0 = ch*512 + (t+1)*64;
      #pragma unroll
      for (int i=0;i<8;i++){
        int rloc = w*16 + i*2 + srow;
        int scol = scolB ^ ((rloc&7)<<4);
        gl_lds16(xb + (size_t)(n0+rloc)*256 + (scol>>1), &xs[(w*16+i*2)*256]);
      }
    }
    #pragma unroll
    for (int ks=0; ks<2; ks++){
      s8v af = *(const s8v*)(pbuf + (w*16+l15)*72 + ks*32 + lg*8);
      #pragma unroll
      for (int et=0; et<4; et++){
        s8v bv = *(const s8v*)(vbuf + (et*16+l15)*72 + ks*32 + lg*8);
        acc[et] = MFMA16(af, bv, acc[et], 0,0,0);
      }
    }
  }
  u16* cp = ctxp + (((size_t)ch*16 + b)*8 + h)*4096;
  #pragma unroll
  for (int et=0; et<4; et++)
    #pragma unroll
    for (int j=0;j<4;j++)
      cp[(w*16+lg*4+j)*64 + et*16+l15] = f2bf(acc[et][j]);
  #pragma unroll
  for (int j=0;j<4;j++){
    float s = ps[j];
    s += __shfl_xor(s,1); s += __shfl_xor(s,2);
    s += __shfl_xor(s,4); s += __shfl_xor(s,8);
    ps[j] = s;
  }
  if (l15==0){
    #pragma unroll
    for (int j=0;j<4;j++){
      int rg = (b*8+h)*64 + w*16 + lg*4 + j;
      Mp[ch*8192+rg]=30.0f; Sp[ch*8192+rg]=ps[j];
    }
  }
}

// ---------------- kernel C: fused combine + G = OW.ctx^T  (one block per bh) -------------
__global__ __launch_bounds__(256) void k_cg(const u16* __restrict__ ctxp, const float* __restrict__ Mp,
    const float* __restrict__ Sp, const u16* __restrict__ owb, u16* __restrict__ G){
  __shared__ u16 ctxs[64*72];
  __shared__ float fs[8][64];
  __shared__ float iSs[64];
  const int bh = blockIdx.x, h = bh&7, tid = threadIdx.x;   // 128 blocks
  const int w = tid>>6, l = tid&63, l15 = l&15, lg = l>>4;
  if (tid < 64){
    float m[8];
    float Mg = -1e30f;
    #pragma unroll
    for (int ch=0;ch<8;ch++){ m[ch] = Mp[ch*8192 + bh*64 + tid]; Mg = fmaxf(Mg, m[ch]); }
    float Sg = 0.f;
    #pragma unroll
    for (int ch=0;ch<8;ch++){
      float fv = __expf(m[ch]-Mg);
      fs[ch][tid] = fv;
      Sg += Sp[ch*8192 + bh*64 + tid]*fv;
    }
    iSs[tid] = 1.0f / Sg;
  }
  __syncthreads();
  {
    const int d = tid>>2, e0 = (tid&3)*16;
    const float fsc = iSs[d];
    #pragma unroll
    for (int i=0;i<16;i++){
      float v = 0.f;
      #pragma unroll
      for (int ch=0;ch<8;ch++)
        v += bf2f(ctxp[(size_t)ch*524288 + (size_t)bh*4096 + d*64 + e0+i]) * fs[ch][d];
      ctxs[d*72 + e0+i] = f2bf(v * fsc);
    }
  }
  s8v a[4][2];
  #pragma unroll
  for (int mt=0; mt<4; mt++)
    #pragma unroll
    for (int ks=0; ks<2; ks++)
      a[mt][ks] = *(const s8v*)(owb + (size_t)(w*64+mt*16+l15)*512 + h*64 + ks*32 + lg*8);
  __syncthreads();
  s8v bD[4][2];
  #pragma unroll
  for (int dt=0; dt<4; dt++)
    #pragma unroll
    for (int ks=0; ks<2; ks++)
      bD[dt][ks] = *(const s8v*)&ctxs[(dt*16+l15)*72 + ks*32 + lg*8];
  f4v acc[4][4];
  #pragma unroll
  for (int mt=0;mt<4;mt++)
    #pragma unroll
    for (int dt=0;dt<4;dt++) acc[mt][dt] = (f4v){0.f,0.f,0.f,0.f};
  #pragma unroll
  for (int ks=0; ks<2; ks++)
    #pragma unroll
    for (int mt=0; mt<4; mt++)
      #pragma unroll
      for (int dt=0; dt<4; dt++)
        acc[mt][dt] = MFMA16(a[mt][ks], bD[dt][ks], acc[mt][dt], 0,0,0);
  u16* gp = G + (size_t)bh*16384;
  #pragma unroll
  for (int mt=0; mt<4; mt++)
    #pragma unroll
    for (int dt=0; dt<4; dt++)
      #pragma unroll
      for (int j=0; j<4; j++)
        gp[(w*64 + mt*16 + lg*4 + j)*64 + dt*16 + l15] = f2bf(acc[mt][dt][j]);
}

// ---------------- kernel D: d-split q-GEMM + fixed-M softmax + cout-split out-GEMM + RMS --
// Wave (ph=w&3, ch2=w>>2): q for ph's 32 px x d-half ch2 (ax[2] -> each bw feeds 2 MFMAs,
// 16 bw reads); out-GEMM for couts ch2*128..+127 x ph's 32 px (aw 16 + ba 4). LDS reads
// 66 -> 36 per wave-head. Fixed-M softmax: cross-wave d-sum via pp (R14/R16-proven).
// 3 barriers/head; stage(h+1) issued after b1 (drains at next b0). Same zero-conflict
// swizzles (keys: WQ row&15=l15, G/qa row&7 = l15&7).
__global__ __launch_bounds__(512,2) void k_qout(const u16* __restrict__ xnT, const u16* __restrict__ wqkv,
    const u16* __restrict__ Gg, const float* __restrict__ ob, const float* __restrict__ onw,
    float* __restrict__ out){
  __shared__ u16 WQb[2][64*256];   // 2x32KB, swizzle (row&15)<<4 bytes
  __shared__ u16 Gb[2][256*64];    // 2x32KB, swizzle (row&7)<<4 bytes
  __shared__ u16 qa[4][32*64];     // 16KB: per-ph [32 n][64 d], XOR (row&7)<<3 u16-units
  __shared__ float pp[4][2][32];   // softmax half-sums
  __shared__ float ssb[4][2][32];  // RMS half-sums
  const int tid = threadIdx.x;
  const int w=tid>>6, l=tid&63, l15=l&15, lg=l>>4;
  const int ph=w&3, ch2=w>>2;
  const int blk=blockIdx.x, b=blk>>5, n0=(blk&31)*128;
  const u16* xb = xnT + ((size_t)b*4096 + n0 + ph*32)*256;
  const u16* Gbase = Gg + (size_t)b*8*16384;
  u16* qaw = qa[ph];
  const int wqRow0 = (l>>5);             // + (i*8+w)*2
  const int wqColB = (l&31)*16;
  const int gRow0  = (l>>3);             // + (i*8+w)*8
  const int gColB  = (l&7)*16;
  // resident xn A-frags: 2 nt sets of 16 px
  s8v ax[2][8];
  #pragma unroll
  for (int nt=0;nt<2;nt++)
    #pragma unroll
    for (int cs=0;cs<8;cs++)
      ax[nt][cs] = *(const s8v*)(xb + (size_t)(nt*16+l15)*256 + cs*32 + lg*8);
  f4v oacc[8][2];
  #pragma unroll
  for (int mt=0;mt<8;mt++){ oacc[mt][0]=(f4v){0.f,0.f,0.f,0.f}; oacc[mt][1]=(f4v){0.f,0.f,0.f,0.f}; }

  // prologue: stage WQ(0), G(0) into buf 0 (roles identical to R13/R18)
  #pragma unroll
  for (int i=0;i<4;i++){
    int row = (i*8+w)*2 + wqRow0;
    int scol = wqColB ^ ((row&15)<<4);
    gl_lds16(wqkv + (size_t)row*256 + (scol>>1), &WQb[0][(i*8+w)*512]);
  }
  #pragma unroll
  for (int i=0;i<4;i++){
    int row = (i*8+w)*8 + gRow0;
    int scol = gColB ^ ((row&7)<<4);
    gl_lds16(Gbase + (size_t)row*64 + (scol>>1), &Gb[0][(i*8+w)*512]);
  }

  for (int h=0; h<8; ++h){
    const int p = h&1;
    __syncthreads();   // b0: stage(h) landed; prev head's buf-p readers done
    // q-GEMM: this wave's d-half (dt = ch2*2 + dt2) for ph's 32 px
    f4v qacc[2][2];
    #pragma unroll
    for (int nt=0;nt<2;nt++){ qacc[nt][0]=(f4v){0.f,0.f,0.f,0.f}; qacc[nt][1]=(f4v){0.f,0.f,0.f,0.f}; }
    #pragma unroll
    for (int dt2=0; dt2<2; dt2++){
      const int drow = (ch2*2+dt2)*16 + l15;
      #pragma unroll
      for (int cs=0; cs<8; cs++){
        s8v bw = *(const s8v*)&WQb[p][drow*256 + ((((cs<<6)|(lg<<4)) ^ (l15<<4))>>1)];
        #pragma unroll
        for (int nt=0;nt<2;nt++)
          qacc[nt][dt2] = MFMA16(ax[nt][cs], bw, qacc[nt][dt2], 0,0,0);
      }
    }
    // fixed-M exp + in-wave partial sums over this half's 32 d
    float e[2][2][4];
    float sj[2][4];
    #pragma unroll
    for (int nt=0;nt<2;nt++)
      #pragma unroll
      for (int j=0;j<4;j++){
        float e0 = __expf(qacc[nt][0][j]-30.0f);
        float e1 = __expf(qacc[nt][1][j]-30.0f);
        e[nt][0][j]=e0; e[nt][1][j]=e1;
        float s = e0+e1;
        s += __shfl_xor(s,1); s += __shfl_xor(s,2);
        s += __shfl_xor(s,4); s += __shfl_xor(s,8);
        sj[nt][j] = s;
        if (l15==0) pp[ph][ch2][nt*16+lg*4+j] = s;
      }
    __syncthreads();   // b1: pp visible
    // stage head h+1 into buf p^1 (drains at next b0: window = qa+out phases)
    if (h<7){
      const u16* wqg = wqkv + (size_t)(h+1)*64*256;
      const u16* gg  = Gbase + (size_t)(h+1)*16384;
      #pragma unroll
      for (int i=0;i<4;i++){
        int row = (i*8+w)*2 + wqRow0;
        int scol = wqColB ^ ((row&15)<<4);
        gl_lds16(wqg + (size_t)row*256 + (scol>>1), &WQb[p^1][(i*8+w)*512]);
      }
      #pragma unroll
      for (int i=0;i<4;i++){
        int row = (i*8+w)*8 + gRow0;
        int scol = gColB ^ ((row&7)<<4);
        gl_lds16(gg + (size_t)row*64 + (scol>>1), &Gb[p^1][(i*8+w)*512]);
      }
    }
    // finish softmax + write P (this wave's d-half of its 32 rows)
    #pragma unroll
    for (int nt=0;nt<2;nt++)
      #pragma unroll
      for (int j=0;j<4;j++){
        const int row = nt*16 + lg*4 + j;
        const float inv = 0.125f/(sj[nt][j] + pp[ph][ch2^1][nt*16+lg*4+j]);
        qaw[((row<<6) + (ch2*2+0)*16 + l15) ^ ((row&7)<<3)] = f2bf(e[nt][0][j]*inv);
        qaw[((row<<6) + (ch2*2+1)*16 + l15) ^ ((row&7)<<3)] = f2bf(e[nt][1][j]*inv);
      }
    __syncthreads();   // b2: qa complete (both halves)
    // out-GEMM: D[cout(ch2 half)][px] += G[cout][d] * P_T[px][d]
    #pragma unroll
    for (int ks=0; ks<2; ks++){
      s8v ba[2];
      #pragma unroll
      for (int nt=0;nt<2;nt++)
        ba[nt] = *(const s8v*)&qaw[((nt*16+l15)<<6) + ((((ks<<6)|(lg<<4)) ^ ((l15&7)<<4))>>1)];
      #pragma unroll
      for (int mt=0; mt<8; mt++){
        s8v aw = *(const s8v*)&Gb[p][(ch2*128 + mt*16 + l15)*64 + ((((ks<<6)|(lg<<4)) ^ ((l15&7)<<4))>>1)];
        #pragma unroll
        for (int nt=0;nt<2;nt++)
          oacc[mt][nt] = MFMA16(aw, ba[nt], oacc[mt][nt], 0,0,0);
      }
    }
  }
  // bias + cross-ch2 RMS + store
  float ss[2] = {0.f, 0.f};
  #pragma unroll
  for (int mt=0;mt<8;mt++){
    const float4 o4 = *(const float4*)&ob[ch2*128 + mt*16 + lg*4];
    #pragma unroll
    for (int nt=0;nt<2;nt++)
      #pragma unroll
      for (int j=0;j<4;j++){
        float v = oacc[mt][nt][j] + ((const float*)&o4)[j];
        oacc[mt][nt][j] = v;
        ss[nt] = fmaf(v,v,ss[nt]);
      }
  }
  #pragma unroll
  for (int nt=0;nt<2;nt++){
    ss[nt] += __shfl_xor(ss[nt], 16);
    ss[nt] += __shfl_xor(ss[nt], 32);
  }
  if (l < 16){
    ssb[ph][ch2][l]    = ss[0];
    ssb[ph][ch2][16+l] = ss[1];
  }
  __syncthreads();
  float rr[2];
  #pragma unroll
  for (int nt=0;nt<2;nt++){
    float sst = ss[nt] + ssb[ph][ch2^1][nt*16+l15];
    rr[nt] = 16.0f / fmaxf(sqrtf(sst), 1e-12f);
  }
  float* op = out + (size_t)b*(256*4096) + n0 + ph*32 + l15;
  #pragma unroll
  for (int mt=0;mt<8;mt++){
    const float4 w4 = *(const float4*)&onw[ch2*128 + mt*16 + lg*4];
    #pragma unroll
    for (int nt=0;nt<2;nt++)
      #pragma unroll
      for (int j=0;j<4;j++){
        int cout = ch2*128 + mt*16 + lg*4 + j;
        op[(size_t)cout*4096 + nt*16] = oacc[mt][nt][j] * rr[nt] * ((const float*)&w4)[j];
      }
  }
}

extern "C" void kernel_launch(void* const* d_in, const int* in_sizes, int n_in,
                              void* d_out, int out_size, void* d_ws, size_t ws_size,
                              hipStream_t stream){
  const float* x    = (const float*)d_in[0];
  const float* nw   = (const float*)d_in[1];
  const float* qkvw = (const float*)d_in[2];
  const float* ow   = (const float*)d_in[3];
  const float* ob   = (const float*)d_in[4];
  const float* onw  = (const float*)d_in[5];
  float* out = (float*)d_out;
  char* ws = (char*)d_ws;
  u16*   xnT  = (u16*)(ws);                    // 33,554,432 B
  u16*   wqkv = (u16*)(ws + 33554432);         //    786,432 B
  u16*   owb  = (u16*)(ws + 34340864);         //    262,144 B
  u16*   ctxp = (u16*)(ws + 35651584);         //  8,388,608 B (dead after k_cg)
  float* Mp   = (float*)(ws + 44040192);       //    262,144 B
  float* Sp   = (float*)(ws + 44302336);       //    262,144 B
  u16*   Gsafe= (u16*)(ws + 44564480);         //  4,194,304 B (disjoint region)
  (void)in_sizes; (void)n_in; (void)out_size; (void)ws_size;

  k_wconv<<<512, 256, 0, stream>>>(qkvw, ow, wqkv, owb);
  k_prep <<<1024, 256, 0, stream>>>(x, nw, xnT);
  k_kv   <<<1024, 256, 0, stream>>>(xnT, wqkv, ctxp, Mp, Sp);
  k_cg   <<<128, 256, 0, stream>>>(ctxp, Mp, Sp, owb, Gsafe);
  k_qout <<<512, 512, 0, stream>>>(xnT, wqkv, Gsafe, ob, onw, out);
}

// Round 20
// 150.914 us; speedup vs baseline: 1.0805x; 1.0805x over previous
//
#include <hip/hip_runtime.h>
#include <hip/hip_bf16.h>

#define C_ 256
#define N_ 4096
#define NH_ 8

typedef unsigned short u16;
typedef unsigned int u32;
typedef __attribute__((ext_vector_type(8))) short s8v;
typedef __attribute__((ext_vector_type(4))) float f4v;

#define MFMA16 __builtin_amdgcn_mfma_f32_16x16x32_bf16

__device__ __forceinline__ float bf2f(u16 b){ union{u32 u; float f;} v; v.u=((u32)b)<<16; return v.f; }
__device__ __forceinline__ u16 f2bf(float f){
  __hip_bfloat16 h = __float2bfloat16(f);
  u16 u; __builtin_memcpy(&u, &h, 2); return u;
}

__device__ __forceinline__ void gl_lds16(const u16* g, u16* l){
  __builtin_amdgcn_global_load_lds((const __attribute__((address_space(1))) u32*)g,
                                   (__attribute__((address_space(3))) u32*)l, 16, 0, 0);
}

// ---------------- kernel A1: pixel rnorm + write xnT[b][n][c] bf16 ----------------
__global__ __launch_bounds__(256) void k_prep(const float* __restrict__ x, const float* __restrict__ nw,
                                              u16* __restrict__ xnT){
  __shared__ float red[256];
  __shared__ float nws[256];
  const int tid = threadIdx.x;
  nws[tid] = nw[tid];
  const int blk = blockIdx.x, b = blk>>6, n0 = (blk&63)*64;
  const int cq = tid>>6, px = tid&63;
  const float* xp = x + (size_t)b*(C_*N_) + (size_t)(cq*64)*N_ + n0 + px;
  float v[64]; float s = 0.f;
  #pragma unroll
  for (int i=0;i<64;i++){ float t = xp[(size_t)i*N_]; v[i]=t; s = fmaf(t,t,s); }
  red[tid] = s;
  __syncthreads();
  const float st = red[px] + red[64+px] + red[128+px] + red[192+px];
  const float r = 16.0f / fmaxf(sqrtf(st), 1e-12f);
  u16* o = xnT + ((size_t)b*4096 + n0 + px)*256 + cq*64;
  #pragma unroll
  for (int i=0;i<64;i+=2){
    *(u32*)(o+i) = (u32)f2bf(v[i]*r*nws[cq*64+i]) | ((u32)f2bf(v[i+1]*r*nws[cq*64+i+1])<<16);
  }
}

// ---------------- kernel A2: weights -> bf16 (float4 vectorized) ----------------
__global__ __launch_bounds__(256) void k_wconv(const float* __restrict__ qkvw, const float* __restrict__ ow,
                                               u16* __restrict__ wqkv, u16* __restrict__ owb){
  int q = blockIdx.x*256 + threadIdx.x;   // 131072 quads (524288 elements)
  int i = q*4;
  const float4 f4 = (i < 393216) ? *(const float4*)&qkvw[i] : *(const float4*)&ow[i-393216];
  u32 lo = (u32)f2bf(f4.x) | ((u32)f2bf(f4.y)<<16);
  u32 hi = (u32)f2bf(f4.z) | ((u32)f2bf(f4.w)<<16);
  u16* dst = (i < 393216) ? (wqkv + i) : (owb + (i-393216));
  *(u32*)dst = lo;
  *(u32*)(dst+2) = hi;
}

// ---------------- kernel B: LDS-staged K/V GEMM + fixed-M softmax (R13 proven) ----------
__global__ __launch_bounds__(256,3) void k_kv(const u16* __restrict__ xnT, const u16* __restrict__ wqkv,
    u16* __restrict__ ctxp, float* __restrict__ Mp, float* __restrict__ Sp){
  __shared__ u16 xs[64*256];     // 32KB staged x tile (swizzled)
  __shared__ u16 pbuf[64*72];
  __shared__ u16 vbuf[64*72];
  const int idx = blockIdx.x;
  const int ch = idx&7, h = (idx>>3)&7, b = idx>>6;
  const int tid=threadIdx.x, w=tid>>6, l=tid&63, l15=l&15, lg=l>>4;
  const int swl = (l15&7)<<4;
  const u16* xb  = xnT + (size_t)b*(4096*256);
  const int srow = (l>>5);
  const int scolB = (l&31)*16;
  s8v ak[8], av[8];
  {
    const u16* wkp = wqkv + (size_t)(512 + h*64 + w*16 + l15)*256 + lg*8;
    #pragma unroll
    for (int cs=0; cs<8; cs++){ ak[cs] = *(const s8v*)(wkp + cs*32); av[cs] = *(const s8v*)(wkp + 131072 + cs*32); }
  }
  int colOff[8];
  #pragma unroll
  for (int cs=0; cs<8; cs++) colOff[cs] = (((cs<<6)+(lg<<4)) ^ swl)>>1;

  f4v acc[4];
  #pragma unroll
  for (int et=0;et<4;et++) acc[et] = (f4v){0.f,0.f,0.f,0.f};
  float ps[4] = {0.f,0.f,0.f,0.f};

  {
    const int n0 = ch*512;
    #pragma unroll
    for (int i=0;i<8;i++){
      int rloc = w*16 + i*2 + srow;
      int scol = scolB ^ ((rloc&7)<<4);
      gl_lds16(xb + (size_t)(n0+rloc)*256 + (scol>>1), &xs[(w*16+i*2)*256]);
    }
  }

  for (int t=0; t<8; ++t){
    __syncthreads();
    f4v kacc[4], vacc[4];
    #pragma unroll
    for (int ns=0;ns<4;ns++){ kacc[ns]=(f4v){0.f,0.f,0.f,0.f}; vacc[ns]=(f4v){0.f,0.f,0.f,0.f}; }
    #pragma unroll
    for (int cs=0; cs<8; cs++){
      #pragma unroll
      for (int ns=0; ns<4; ns++){
        s8v bfr = *(const s8v*)&xs[(ns*16+l15)*256 + colOff[cs]];
        kacc[ns] = MFMA16(ak[cs], bfr, kacc[ns], 0,0,0);
        vacc[ns] = MFMA16(av[cs], bfr, vacc[ns], 0,0,0);
      }
    }
    #pragma unroll
    for (int j=0;j<4;j++){
      const int row = w*16 + lg*4 + j;
      #pragma unroll
      for (int ns=0;ns<4;ns++){
        float e = __expf(kacc[ns][j] - 30.0f);
        ps[j] += e;
        pbuf[row*72 + ns*16+l15] = f2bf(e);
        vbuf[row*72 + ns*16+l15] = f2bf(vacc[ns][j]);
      }
    }
    __syncthreads();
    if (t<7){
      const int n0 = ch*512 + (t+1)*64;
      #pragma unroll
      for (int i=0;i<8;i++){
        int rloc = w*16 + i*2 + srow;
        int scol = scolB ^ ((rloc&7)<<4);
        gl_lds16(xb + (size_t)(n0+rloc)*256 + (scol>>1), &xs[(w*16+i*2)*256]);
      }
    }
    #pragma unroll
    for (int ks=0; ks<2; ks++){
      s8v af = *(const s8v*)(pbuf + (w*16+l15)*72 + ks*32 + lg*8);
      #pragma unroll
      for (int et=0; et<4; et++){
        s8v bv = *(const s8v*)(vbuf + (et*16+l15)*72 + ks*32 + lg*8);
        acc[et] = MFMA16(af, bv, acc[et], 0,0,0);
      }
    }
  }
  u16* cp = ctxp + (((size_t)ch*16 + b)*8 + h)*4096;
  #pragma unroll
  for (int et=0; et<4; et++)
    #pragma unroll
    for (int j=0;j<4;j++)
      cp[(w*16+lg*4+j)*64 + et*16+l15] = f2bf(acc[et][j]);
  #pragma unroll
  for (int j=0;j<4;j++){
    float s = ps[j];
    s += __shfl_xor(s,1); s += __shfl_xor(s,2);
    s += __shfl_xor(s,4); s += __shfl_xor(s,8);
    ps[j] = s;
  }
  if (l15==0){
    #pragma unroll
    for (int j=0;j<4;j++){
      int rg = (b*8+h)*64 + w*16 + lg*4 + j;
      Mp[ch*8192+rg]=30.0f; Sp[ch*8192+rg]=ps[j];
    }
  }
}

// ---------------- kernel C: fused combine + G = OW.ctx^T  (one block per bh) -------------
__global__ __launch_bounds__(256) void k_cg(const u16* __restrict__ ctxp, const float* __restrict__ Mp,
    const float* __restrict__ Sp, const u16* __restrict__ owb, u16* __restrict__ G){
  __shared__ u16 ctxs[64*72];
  __shared__ float fs[8][64];
  __shared__ float iSs[64];
  const int bh = blockIdx.x, h = bh&7, tid = threadIdx.x;   // 128 blocks
  const int w = tid>>6, l = tid&63, l15 = l&15, lg = l>>4;
  if (tid < 64){
    float m[8];
    float Mg = -1e30f;
    #pragma unroll
    for (int ch=0;ch<8;ch++){ m[ch] = Mp[ch*8192 + bh*64 + tid]; Mg = fmaxf(Mg, m[ch]); }
    float Sg = 0.f;
    #pragma unroll
    for (int ch=0;ch<8;ch++){
      float fv = __expf(m[ch]-Mg);
      fs[ch][tid] = fv;
      Sg += Sp[ch*8192 + bh*64 + tid]*fv;
    }
    iSs[tid] = 1.0f / Sg;
  }
  __syncthreads();
  {
    const int d = tid>>2, e0 = (tid&3)*16;
    const float fsc = iSs[d];
    #pragma unroll
    for (int i=0;i<16;i++){
      float v = 0.f;
      #pragma unroll
      for (int ch=0;ch<8;ch++)
        v += bf2f(ctxp[(size_t)ch*524288 + (size_t)bh*4096 + d*64 + e0+i]) * fs[ch][d];
      ctxs[d*72 + e0+i] = f2bf(v * fsc);
    }
  }
  s8v a[4][2];
  #pragma unroll
  for (int mt=0; mt<4; mt++)
    #pragma unroll
    for (int ks=0; ks<2; ks++)
      a[mt][ks] = *(const s8v*)(owb + (size_t)(w*64+mt*16+l15)*512 + h*64 + ks*32 + lg*8);
  __syncthreads();
  s8v bD[4][2];
  #pragma unroll
  for (int dt=0; dt<4; dt++)
    #pragma unroll
    for (int ks=0; ks<2; ks++)
      bD[dt][ks] = *(const s8v*)&ctxs[(dt*16+l15)*72 + ks*32 + lg*8];
  f4v acc[4][4];
  #pragma unroll
  for (int mt=0;mt<4;mt++)
    #pragma unroll
    for (int dt=0;dt<4;dt++) acc[mt][dt] = (f4v){0.f,0.f,0.f,0.f};
  #pragma unroll
  for (int ks=0; ks<2; ks++)
    #pragma unroll
    for (int mt=0; mt<4; mt++)
      #pragma unroll
      for (int dt=0; dt<4; dt++)
        acc[mt][dt] = MFMA16(a[mt][ks], bD[dt][ks], acc[mt][dt], 0,0,0);
  u16* gp = G + (size_t)bh*16384;
  #pragma unroll
  for (int mt=0; mt<4; mt++)
    #pragma unroll
    for (int dt=0; dt<4; dt++)
      #pragma unroll
      for (int j=0; j<4; j++)
        gp[(w*64 + mt*16 + lg*4 + j)*64 + dt*16 + l15] = f2bf(acc[mt][dt][j]);
}

// ---------------- kernel D: q-GEMM + fixed-M softmax + out-GEMM(G) + bias + RMS ----------
// R18 proven structure (73.7us): 1 barrier/head, double-buffered WQ/G, zero-conflict
// swizzles. Added: bijective XCD swizzle so all same-b blocks (sharing G slab + xnT slab)
// land on the same XCD's L2 (grid 512 = 64/XCD exactly).
__global__ __launch_bounds__(512,2) void k_qout(const u16* __restrict__ xnT, const u16* __restrict__ wqkv,
    const u16* __restrict__ Gg, const float* __restrict__ ob, const float* __restrict__ onw,
    float* __restrict__ out){
  __shared__ u16 WQb[2][64*256];   // 2x32KB, swizzle (row&15)<<4 bytes
  __shared__ u16 Gb[2][256*64];    // 2x32KB, swizzle (row&7)<<4 bytes
  __shared__ u16 qa[8][1024];      // per-wave [16 n][64 d], XOR (row&7)<<3 u16-units
  const int tid = threadIdx.x;
  const int w=tid>>6, l=tid&63, l15=l&15, lg=l>>4;
  // XCD swizzle: raw = xcd + slot*8 + half*256 -> logical blk = (b,t) with b = half*8+xcd
  const int raw = blockIdx.x;
  const int b = ((raw>>8)<<3) + (raw&7);   // half*8 + xcd
  const int t = (raw>>3)&31;
  const int n0 = t*128 + w*16;
  const u16* xb = xnT + ((size_t)b*4096 + n0)*256;
  const u16* Gbase = Gg + (size_t)b*8*16384;
  u16* qaw = qa[w];
  const int wqRow0 = (l>>5);             // + (i*8+w)*2
  const int wqColB = (l&31)*16;
  const int gRow0  = (l>>3);             // + (i*8+w)*8
  const int gColB  = (l&7)*16;
  // resident xn A-frags (rows n)
  s8v ax[8];
  #pragma unroll
  for (int cs=0;cs<8;cs++) ax[cs] = *(const s8v*)(xb + (size_t)l15*256 + cs*32 + lg*8);
  f4v oacc[16];
  #pragma unroll
  for (int mt=0;mt<16;mt++) oacc[mt] = (f4v){0.f,0.f,0.f,0.f};

  // prologue: stage WQ(0), G(0) into buf 0
  #pragma unroll
  for (int i=0;i<4;i++){
    int row = (i*8+w)*2 + wqRow0;
    int scol = wqColB ^ ((row&15)<<4);
    gl_lds16(wqkv + (size_t)row*256 + (scol>>1), &WQb[0][(i*8+w)*512]);
  }
  #pragma unroll
  for (int i=0;i<4;i++){
    int row = (i*8+w)*8 + gRow0;
    int scol = gColB ^ ((row&7)<<4);
    gl_lds16(Gbase + (size_t)row*64 + (scol>>1), &Gb[0][(i*8+w)*512]);
  }

  for (int h=0; h<8; ++h){
    const int p = h&1;
    __syncthreads();   // stage(h) landed (vmcnt+lgkm drained); prev head's buf-p readers done
    // stage head h+1 into buf p^1 (overlaps this whole head)
    if (h<7){
      const u16* wqg = wqkv + (size_t)(h+1)*64*256;
      const u16* gg  = Gbase + (size_t)(h+1)*16384;
      #pragma unroll
      for (int i=0;i<4;i++){
        int row = (i*8+w)*2 + wqRow0;
        int scol = wqColB ^ ((row&15)<<4);
        gl_lds16(wqg + (size_t)row*256 + (scol>>1), &WQb[p^1][(i*8+w)*512]);
      }
      #pragma unroll
      for (int i=0;i<4;i++){
        int row = (i*8+w)*8 + gRow0;
        int scol = gColB ^ ((row&7)<<4);
        gl_lds16(gg + (size_t)row*64 + (scol>>1), &Gb[p^1][(i*8+w)*512]);
      }
    }
    // q-GEMM: D[n-local][dout]  (A = xn rows n, B = WQ rows dout)
    f4v qacc[4];
    #pragma unroll
    for (int dt=0;dt<4;dt++) qacc[dt] = (f4v){0.f,0.f,0.f,0.f};
    #pragma unroll
    for (int dt=0; dt<4; dt++){
      #pragma unroll
      for (int cs=0; cs<8; cs++){
        s8v bw = *(const s8v*)&WQb[p][(dt*16+l15)*256 + ((((cs<<6)|(lg<<4)) ^ (l15<<4))>>1)];
        qacc[dt] = MFMA16(ax[cs], bw, qacc[dt], 0,0,0);
      }
    }
    // fixed-M softmax over d per pixel row (n = lg*4+j): no max chain, sum-reduce only
    #pragma unroll
    for (int j=0;j<4;j++){
      float e[4]; float s = 0.f;
      #pragma unroll
      for (int dt=0;dt<4;dt++){ e[dt] = __expf(qacc[dt][j]-30.0f); s += e[dt]; }
      s += __shfl_xor(s,1); s += __shfl_xor(s,2);
      s += __shfl_xor(s,4); s += __shfl_xor(s,8);
      const float inv = 0.125f/s;
      #pragma unroll
      for (int dt=0;dt<4;dt++){
        int row = lg*4+j;
        qaw[((row<<6) + dt*16 + l15) ^ ((row&7)<<3)] = f2bf(e[dt]*inv);
      }
    }
    // out-GEMM: D[cout][n] += G[cout][d] * P_T[n][d]  (A = G rows cout, B = qa rows n)
    #pragma unroll
    for (int ks=0; ks<2; ks++){
      s8v ba = *(const s8v*)&qaw[(l15<<6) + ((((ks<<6)|(lg<<4)) ^ ((l15&7)<<4))>>1)];
      #pragma unroll
      for (int mt=0; mt<16; mt++){
        s8v aw = *(const s8v*)&Gb[p][(mt*16+l15)*64 + ((((ks<<6)|(lg<<4)) ^ ((l15&7)<<4))>>1)];
        oacc[mt] = MFMA16(aw, ba, oacc[mt], 0,0,0);
      }
    }
  }
  // bias + RMS over channels + store (ob/onw from global: L2-hot float4 loads)
  float ss = 0.f;
  #pragma unroll
  for (int mt=0;mt<16;mt++){
    const float4 o4 = *(const float4*)&ob[mt*16 + lg*4];
    #pragma unroll
    for (int j=0;j<4;j++){
      float v = oacc[mt][j] + ((const float*)&o4)[j];
      oacc[mt][j] = v;
      ss = fmaf(v,v,ss);
    }
  }
  ss += __shfl_xor(ss, 16);
  ss += __shfl_xor(ss, 32);
  const float r = 16.0f / fmaxf(sqrtf(ss), 1e-12f);
  float* op = out + (size_t)b*(256*4096) + n0 + l15;
  #pragma unroll
  for (int mt=0;mt<16;mt++){
    const float4 w4 = *(const float4*)&onw[mt*16 + lg*4];
    #pragma unroll
    for (int j=0;j<4;j++){
      int cout = mt*16+lg*4+j;
      op[(size_t)cout*4096] = oacc[mt][j] * r * ((const float*)&w4)[j];
    }
  }
}

extern "C" void kernel_launch(void* const* d_in, const int* in_sizes, int n_in,
                              void* d_out, int out_size, void* d_ws, size_t ws_size,
                              hipStream_t stream){
  const float* x    = (const float*)d_in[0];
  const float* nw   = (const float*)d_in[1];
  const float* qkvw = (const float*)d_in[2];
  const float* ow   = (const float*)d_in[3];
  const float* ob   = (const float*)d_in[4];
  const float* onw  = (const float*)d_in[5];
  float* out = (float*)d_out;
  char* ws = (char*)d_ws;
  u16*   xnT  = (u16*)(ws);                    // 33,554,432 B
  u16*   wqkv = (u16*)(ws + 33554432);         //    786,432 B
  u16*   owb  = (u16*)(ws + 34340864);         //    262,144 B
  u16*   ctxp = (u16*)(ws + 35651584);         //  8,388,608 B (dead after k_cg)
  float* Mp   = (float*)(ws + 44040192);       //    262,144 B
  float* Sp   = (float*)(ws + 44302336);       //    262,144 B
  u16*   Gsafe= (u16*)(ws + 44564480);         //  4,194,304 B (disjoint region)
  (void)in_sizes; (void)n_in; (void)out_size; (void)ws_size;

  k_wconv<<<512, 256, 0, stream>>>(qkvw, ow, wqkv, owb);
  k_prep <<<1024, 256, 0, stream>>>(x, nw, xnT);
  k_kv   <<<1024, 256, 0, stream>>>(xnT, wqkv, ctxp, Mp, Sp);
  k_cg   <<<128, 256, 0, stream>>>(ctxp, Mp, Sp, owb, Gsafe);
  k_qout <<<512, 512, 0, stream>>>(xnT, wqkv, Gsafe, ob, onw, out);
}

// Round 21
// 147.759 us; speedup vs baseline: 1.1036x; 1.0214x over previous
//
#include <hip/hip_runtime.h>
#include <hip/hip_bf16.h>

#define C_ 256
#define N_ 4096
#define NH_ 8

typedef unsigned short u16;
typedef unsigned int u32;
typedef __attribute__((ext_vector_type(8))) short s8v;
typedef __attribute__((ext_vector_type(4))) float f4v;

#define MFMA16 __builtin_amdgcn_mfma_f32_16x16x32_bf16

__device__ __forceinline__ float bf2f(u16 b){ union{u32 u; float f;} v; v.u=((u32)b)<<16; return v.f; }
__device__ __forceinline__ u16 f2bf(float f){
  __hip_bfloat16 h = __float2bfloat16(f);
  u16 u; __builtin_memcpy(&u, &h, 2); return u;
}

__device__ __forceinline__ void gl_lds16(const u16* g, u16* l){
  __builtin_amdgcn_global_load_lds((const __attribute__((address_space(1))) u32*)g,
                                   (__attribute__((address_space(3))) u32*)l, 16, 0, 0);
}

// ---------------- kernel A1: pixel rnorm + write xnT[b][n][c] bf16 ----------------
__global__ __launch_bounds__(256) void k_prep(const float* __restrict__ x, const float* __restrict__ nw,
                                              u16* __restrict__ xnT){
  __shared__ float red[256];
  __shared__ float nws[256];
  const int tid = threadIdx.x;
  nws[tid] = nw[tid];
  const int blk = blockIdx.x, b = blk>>6, n0 = (blk&63)*64;
  const int cq = tid>>6, px = tid&63;
  const float* xp = x + (size_t)b*(C_*N_) + (size_t)(cq*64)*N_ + n0 + px;
  float v[64]; float s = 0.f;
  #pragma unroll
  for (int i=0;i<64;i++){ float t = xp[(size_t)i*N_]; v[i]=t; s = fmaf(t,t,s); }
  red[tid] = s;
  __syncthreads();
  const float st = red[px] + red[64+px] + red[128+px] + red[192+px];
  const float r = 16.0f / fmaxf(sqrtf(st), 1e-12f);
  u16* o = xnT + ((size_t)b*4096 + n0 + px)*256 + cq*64;
  #pragma unroll
  for (int i=0;i<64;i+=2){
    *(u32*)(o+i) = (u32)f2bf(v[i]*r*nws[cq*64+i]) | ((u32)f2bf(v[i+1]*r*nws[cq*64+i+1])<<16);
  }
}

// ---------------- kernel A2: weights -> bf16 (float4 vectorized) ----------------
__global__ __launch_bounds__(256) void k_wconv(const float* __restrict__ qkvw, const float* __restrict__ ow,
                                               u16* __restrict__ wqkv, u16* __restrict__ owb){
  int q = blockIdx.x*256 + threadIdx.x;   // 131072 quads (524288 elements)
  int i = q*4;
  const float4 f4 = (i < 393216) ? *(const float4*)&qkvw[i] : *(const float4*)&ow[i-393216];
  u32 lo = (u32)f2bf(f4.x) | ((u32)f2bf(f4.y)<<16);
  u32 hi = (u32)f2bf(f4.z) | ((u32)f2bf(f4.w)<<16);
  u16* dst = (i < 393216) ? (wqkv + i) : (owb + (i-393216));
  *(u32*)dst = lo;
  *(u32*)(dst+2) = hi;
}

// ---------------- kernel B: LDS-staged K/V GEMM + fixed-M softmax (ch=4: 1024px chunks) --
// R13-proven inner loop; chunk doubled to 16 tiles so per-block overheads (64-VGPR weight
// prologue, acc init, first stage drain, tail) amortize 2x. Grid 512 (idx = ch + 4h + 32b).
__global__ __launch_bounds__(256,3) void k_kv(const u16* __restrict__ xnT, const u16* __restrict__ wqkv,
    u16* __restrict__ ctxp, float* __restrict__ Mp, float* __restrict__ Sp){
  __shared__ u16 xs[64*256];     // 32KB staged x tile (swizzled)
  __shared__ u16 pbuf[64*72];
  __shared__ u16 vbuf[64*72];
  const int idx = blockIdx.x;
  const int ch = idx&3, h = (idx>>2)&7, b = idx>>5;
  const int tid=threadIdx.x, w=tid>>6, l=tid&63, l15=l&15, lg=l>>4;
  const int swl = (l15&7)<<4;
  const u16* xb  = xnT + (size_t)b*(4096*256);
  const int srow = (l>>5);
  const int scolB = (l&31)*16;
  s8v ak[8], av[8];
  {
    const u16* wkp = wqkv + (size_t)(512 + h*64 + w*16 + l15)*256 + lg*8;
    #pragma unroll
    for (int cs=0; cs<8; cs++){ ak[cs] = *(const s8v*)(wkp + cs*32); av[cs] = *(const s8v*)(wkp + 131072 + cs*32); }
  }
  int colOff[8];
  #pragma unroll
  for (int cs=0; cs<8; cs++) colOff[cs] = (((cs<<6)+(lg<<4)) ^ swl)>>1;

  f4v acc[4];
  #pragma unroll
  for (int et=0;et<4;et++) acc[et] = (f4v){0.f,0.f,0.f,0.f};
  float ps[4] = {0.f,0.f,0.f,0.f};

  {
    const int n0 = ch*1024;
    #pragma unroll
    for (int i=0;i<8;i++){
      int rloc = w*16 + i*2 + srow;
      int scol = scolB ^ ((rloc&7)<<4);
      gl_lds16(xb + (size_t)(n0+rloc)*256 + (scol>>1), &xs[(w*16+i*2)*256]);
    }
  }

  for (int t=0; t<16; ++t){
    __syncthreads();
    f4v kacc[4], vacc[4];
    #pragma unroll
    for (int ns=0;ns<4;ns++){ kacc[ns]=(f4v){0.f,0.f,0.f,0.f}; vacc[ns]=(f4v){0.f,0.f,0.f,0.f}; }
    #pragma unroll
    for (int cs=0; cs<8; cs++){
      #pragma unroll
      for (int ns=0; ns<4; ns++){
        s8v bfr = *(const s8v*)&xs[(ns*16+l15)*256 + colOff[cs]];
        kacc[ns] = MFMA16(ak[cs], bfr, kacc[ns], 0,0,0);
        vacc[ns] = MFMA16(av[cs], bfr, vacc[ns], 0,0,0);
      }
    }
    #pragma unroll
    for (int j=0;j<4;j++){
      const int row = w*16 + lg*4 + j;
      #pragma unroll
      for (int ns=0;ns<4;ns++){
        float e = __expf(kacc[ns][j] - 30.0f);
        ps[j] += e;
        pbuf[row*72 + ns*16+l15] = f2bf(e);
        vbuf[row*72 + ns*16+l15] = f2bf(vacc[ns][j]);
      }
    }
    __syncthreads();
    if (t<15){
      const int n0 = ch*1024 + (t+1)*64;
      #pragma unroll
      for (int i=0;i<8;i++){
        int rloc = w*16 + i*2 + srow;
        int scol = scolB ^ ((rloc&7)<<4);
        gl_lds16(xb + (size_t)(n0+rloc)*256 + (scol>>1), &xs[(w*16+i*2)*256]);
      }
    }
    #pragma unroll
    for (int ks=0; ks<2; ks++){
      s8v af = *(const s8v*)(pbuf + (w*16+l15)*72 + ks*32 + lg*8);
      #pragma unroll
      for (int et=0; et<4; et++){
        s8v bv = *(const s8v*)(vbuf + (et*16+l15)*72 + ks*32 + lg*8);
        acc[et] = MFMA16(af, bv, acc[et], 0,0,0);
      }
    }
  }
  u16* cp = ctxp + (((size_t)ch*16 + b)*8 + h)*4096;
  #pragma unroll
  for (int et=0; et<4; et++)
    #pragma unroll
    for (int j=0;j<4;j++)
      cp[(w*16+lg*4+j)*64 + et*16+l15] = f2bf(acc[et][j]);
  #pragma unroll
  for (int j=0;j<4;j++){
    float s = ps[j];
    s += __shfl_xor(s,1); s += __shfl_xor(s,2);
    s += __shfl_xor(s,4); s += __shfl_xor(s,8);
    ps[j] = s;
  }
  if (l15==0){
    #pragma unroll
    for (int j=0;j<4;j++){
      int rg = (b*8+h)*64 + w*16 + lg*4 + j;
      Mp[ch*8192+rg]=30.0f; Sp[ch*8192+rg]=ps[j];
    }
  }
}

// ---------------- kernel C: fused combine (4 chunks) + G = OW.ctx^T ----------------------
__global__ __launch_bounds__(256) void k_cg(const u16* __restrict__ ctxp, const float* __restrict__ Mp,
    const float* __restrict__ Sp, const u16* __restrict__ owb, u16* __restrict__ G){
  __shared__ u16 ctxs[64*72];
  __shared__ float fs[4][64];
  __shared__ float iSs[64];
  const int bh = blockIdx.x, h = bh&7, tid = threadIdx.x;   // 128 blocks
  const int w = tid>>6, l = tid&63, l15 = l&15, lg = l>>4;
  if (tid < 64){
    float m[4];
    float Mg = -1e30f;
    #pragma unroll
    for (int ch=0;ch<4;ch++){ m[ch] = Mp[ch*8192 + bh*64 + tid]; Mg = fmaxf(Mg, m[ch]); }
    float Sg = 0.f;
    #pragma unroll
    for (int ch=0;ch<4;ch++){
      float fv = __expf(m[ch]-Mg);
      fs[ch][tid] = fv;
      Sg += Sp[ch*8192 + bh*64 + tid]*fv;
    }
    iSs[tid] = 1.0f / Sg;
  }
  __syncthreads();
  {
    const int d = tid>>2, e0 = (tid&3)*16;
    const float fsc = iSs[d];
    #pragma unroll
    for (int i=0;i<16;i++){
      float v = 0.f;
      #pragma unroll
      for (int ch=0;ch<4;ch++)
        v += bf2f(ctxp[(size_t)ch*524288 + (size_t)bh*4096 + d*64 + e0+i]) * fs[ch][d];
      ctxs[d*72 + e0+i] = f2bf(v * fsc);
    }
  }
  s8v a[4][2];
  #pragma unroll
  for (int mt=0; mt<4; mt++)
    #pragma unroll
    for (int ks=0; ks<2; ks++)
      a[mt][ks] = *(const s8v*)(owb + (size_t)(w*64+mt*16+l15)*512 + h*64 + ks*32 + lg*8);
  __syncthreads();
  s8v bD[4][2];
  #pragma unroll
  for (int dt=0; dt<4; dt++)
    #pragma unroll
    for (int ks=0; ks<2; ks++)
      bD[dt][ks] = *(const s8v*)&ctxs[(dt*16+l15)*72 + ks*32 + lg*8];
  f4v acc[4][4];
  #pragma unroll
  for (int mt=0;mt<4;mt++)
    #pragma unroll
    for (int dt=0;dt<4;dt++) acc[mt][dt] = (f4v){0.f,0.f,0.f,0.f};
  #pragma unroll
  for (int ks=0; ks<2; ks++)
    #pragma unroll
    for (int mt=0; mt<4; mt++)
      #pragma unroll
      for (int dt=0; dt<4; dt++)
        acc[mt][dt] = MFMA16(a[mt][ks], bD[dt][ks], acc[mt][dt], 0,0,0);
  u16* gp = G + (size_t)bh*16384;
  #pragma unroll
  for (int mt=0; mt<4; mt++)
    #pragma unroll
    for (int dt=0; dt<4; dt++)
      #pragma unroll
      for (int j=0; j<4; j++)
        gp[(w*64 + mt*16 + lg*4 + j)*64 + dt*16 + l15] = f2bf(acc[mt][dt][j]);
}

// ---------------- kernel D: q-GEMM + fixed-M softmax + out-GEMM(G) + bias + RMS ----------
// R18 proven structure + XCD swizzle (R20: FETCH -40%, duration-neutral, kept as free).
__global__ __launch_bounds__(512,2) void k_qout(const u16* __restrict__ xnT, const u16* __restrict__ wqkv,
    const u16* __restrict__ Gg, const float* __restrict__ ob, const float* __restrict__ onw,
    float* __restrict__ out){
  __shared__ u16 WQb[2][64*256];   // 2x32KB, swizzle (row&15)<<4 bytes
  __shared__ u16 Gb[2][256*64];    // 2x32KB, swizzle (row&7)<<4 bytes
  __shared__ u16 qa[8][1024];      // per-wave [16 n][64 d], XOR (row&7)<<3 u16-units
  const int tid = threadIdx.x;
  const int w=tid>>6, l=tid&63, l15=l&15, lg=l>>4;
  const int raw = blockIdx.x;
  const int b = ((raw>>8)<<3) + (raw&7);   // half*8 + xcd
  const int t = (raw>>3)&31;
  const int n0 = t*128 + w*16;
  const u16* xb = xnT + ((size_t)b*4096 + n0)*256;
  const u16* Gbase = Gg + (size_t)b*8*16384;
  u16* qaw = qa[w];
  const int wqRow0 = (l>>5);             // + (i*8+w)*2
  const int wqColB = (l&31)*16;
  const int gRow0  = (l>>3);             // + (i*8+w)*8
  const int gColB  = (l&7)*16;
  s8v ax[8];
  #pragma unroll
  for (int cs=0;cs<8;cs++) ax[cs] = *(const s8v*)(xb + (size_t)l15*256 + cs*32 + lg*8);
  f4v oacc[16];
  #pragma unroll
  for (int mt=0;mt<16;mt++) oacc[mt] = (f4v){0.f,0.f,0.f,0.f};

  #pragma unroll
  for (int i=0;i<4;i++){
    int row = (i*8+w)*2 + wqRow0;
    int scol = wqColB ^ ((row&15)<<4);
    gl_lds16(wqkv + (size_t)row*256 + (scol>>1), &WQb[0][(i*8+w)*512]);
  }
  #pragma unroll
  for (int i=0;i<4;i++){
    int row = (i*8+w)*8 + gRow0;
    int scol = gColB ^ ((row&7)<<4);
    gl_lds16(Gbase + (size_t)row*64 + (scol>>1), &Gb[0][(i*8+w)*512]);
  }

  for (int h=0; h<8; ++h){
    const int p = h&1;
    __syncthreads();
    if (h<7){
      const u16* wqg = wqkv + (size_t)(h+1)*64*256;
      const u16* gg  = Gbase + (size_t)(h+1)*16384;
      #pragma unroll
      for (int i=0;i<4;i++){
        int row = (i*8+w)*2 + wqRow0;
        int scol = wqColB ^ ((row&15)<<4);
        gl_lds16(wqg + (size_t)row*256 + (scol>>1), &WQb[p^1][(i*8+w)*512]);
      }
      #pragma unroll
      for (int i=0;i<4;i++){
        int row = (i*8+w)*8 + gRow0;
        int scol = gColB ^ ((row&7)<<4);
        gl_lds16(gg + (size_t)row*64 + (scol>>1), &Gb[p^1][(i*8+w)*512]);
      }
    }
    f4v qacc[4];
    #pragma unroll
    for (int dt=0;dt<4;dt++) qacc[dt] = (f4v){0.f,0.f,0.f,0.f};
    #pragma unroll
    for (int dt=0; dt<4; dt++){
      #pragma unroll
      for (int cs=0; cs<8; cs++){
        s8v bw = *(const s8v*)&WQb[p][(dt*16+l15)*256 + ((((cs<<6)|(lg<<4)) ^ (l15<<4))>>1)];
        qacc[dt] = MFMA16(ax[cs], bw, qacc[dt], 0,0,0);
      }
    }
    #pragma unroll
    for (int j=0;j<4;j++){
      float e[4]; float s = 0.f;
      #pragma unroll
      for (int dt=0;dt<4;dt++){ e[dt] = __expf(qacc[dt][j]-30.0f); s += e[dt]; }
      s += __shfl_xor(s,1); s += __shfl_xor(s,2);
      s += __shfl_xor(s,4); s += __shfl_xor(s,8);
      const float inv = 0.125f/s;
      #pragma unroll
      for (int dt=0;dt<4;dt++){
        int row = lg*4+j;
        qaw[((row<<6) + dt*16 + l15) ^ ((row&7)<<3)] = f2bf(e[dt]*inv);
      }
    }
    #pragma unroll
    for (int ks=0; ks<2; ks++){
      s8v ba = *(const s8v*)&qaw[(l15<<6) + ((((ks<<6)|(lg<<4)) ^ ((l15&7)<<4))>>1)];
      #pragma unroll
      for (int mt=0; mt<16; mt++){
        s8v aw = *(const s8v*)&Gb[p][(mt*16+l15)*64 + ((((ks<<6)|(lg<<4)) ^ ((l15&7)<<4))>>1)];
        oacc[mt] = MFMA16(aw, ba, oacc[mt], 0,0,0);
      }
    }
  }
  float ss = 0.f;
  #pragma unroll
  for (int mt=0;mt<16;mt++){
    const float4 o4 = *(const float4*)&ob[mt*16 + lg*4];
    #pragma unroll
    for (int j=0;j<4;j++){
      float v = oacc[mt][j] + ((const float*)&o4)[j];
      oacc[mt][j] = v;
      ss = fmaf(v,v,ss);
    }
  }
  ss += __shfl_xor(ss, 16);
  ss += __shfl_xor(ss, 32);
  const float r = 16.0f / fmaxf(sqrtf(ss), 1e-12f);
  float* op = out + (size_t)b*(256*4096) + n0 + l15;
  #pragma unroll
  for (int mt=0;mt<16;mt++){
    const float4 w4 = *(const float4*)&onw[mt*16 + lg*4];
    #pragma unroll
    for (int j=0;j<4;j++){
      int cout = mt*16+lg*4+j;
      op[(size_t)cout*4096] = oacc[mt][j] * r * ((const float*)&w4)[j];
    }
  }
}

extern "C" void kernel_launch(void* const* d_in, const int* in_sizes, int n_in,
                              void* d_out, int out_size, void* d_ws, size_t ws_size,
                              hipStream_t stream){
  const float* x    = (const float*)d_in[0];
  const float* nw   = (const float*)d_in[1];
  const float* qkvw = (const float*)d_in[2];
  const float* ow   = (const float*)d_in[3];
  const float* ob   = (const float*)d_in[4];
  const float* onw  = (const float*)d_in[5];
  float* out = (float*)d_out;
  char* ws = (char*)d_ws;
  u16*   xnT  = (u16*)(ws);                    // 33,554,432 B
  u16*   wqkv = (u16*)(ws + 33554432);         //    786,432 B
  u16*   owb  = (u16*)(ws + 34340864);         //    262,144 B
  u16*   ctxp = (u16*)(ws + 35651584);         //  4,194,304 B (4 chunks bf16)
  float* Mp   = (float*)(ws + 44040192);       //    131,072 B
  float* Sp   = (float*)(ws + 44302336);       //    131,072 B
  u16*   Gsafe= (u16*)(ws + 44564480);         //  4,194,304 B (disjoint region)
  (void)in_sizes; (void)n_in; (void)out_size; (void)ws_size;

  k_wconv<<<512, 256, 0, stream>>>(qkvw, ow, wqkv, owb);
  k_prep <<<1024, 256, 0, stream>>>(x, nw, xnT);
  k_kv   <<<512, 256, 0, stream>>>(xnT, wqkv, ctxp, Mp, Sp);
  k_cg   <<<128, 256, 0, stream>>>(ctxp, Mp, Sp, owb, Gsafe);
  k_qout <<<512, 512, 0, stream>>>(xnT, wqkv, Gsafe, ob, onw, out);
}

// Round 22
// 143.137 us; speedup vs baseline: 1.1393x; 1.0323x over previous
//
#include <hip/hip_runtime.h>
#include <hip/hip_bf16.h>

#define C_ 256
#define N_ 4096
#define NH_ 8

typedef unsigned short u16;
typedef unsigned int u32;
typedef __attribute__((ext_vector_type(8))) short s8v;
typedef __attribute__((ext_vector_type(4))) float f4v;

#define MFMA16 __builtin_amdgcn_mfma_f32_16x16x32_bf16

__device__ __forceinline__ float bf2f(u16 b){ union{u32 u; float f;} v; v.u=((u32)b)<<16; return v.f; }
__device__ __forceinline__ u16 f2bf(float f){
  __hip_bfloat16 h = __float2bfloat16(f);
  u16 u; __builtin_memcpy(&u, &h, 2); return u;
}

__device__ __forceinline__ void gl_lds16(const u16* g, u16* l){
  __builtin_amdgcn_global_load_lds((const __attribute__((address_space(1))) u32*)g,
                                   (__attribute__((address_space(3))) u32*)l, 16, 0, 0);
}

// ---------------- kernel A: fused pixel-rnorm (blocks 0..1023) + weight conv (1024..1535) --
__global__ __launch_bounds__(256) void k_prep(const float* __restrict__ x, const float* __restrict__ nw,
                                              u16* __restrict__ xnT,
                                              const float* __restrict__ qkvw, const float* __restrict__ ow,
                                              u16* __restrict__ wqkv, u16* __restrict__ owb){
  __shared__ float red[256];
  __shared__ float nws[256];
  const int tid = threadIdx.x;
  const int blk = blockIdx.x;
  if (blk >= 1024){
    // weight conversion branch (float4 vectorized)
    int q = (blk-1024)*256 + tid;   // 131072 quads
    int i = q*4;
    const float4 f4 = (i < 393216) ? *(const float4*)&qkvw[i] : *(const float4*)&ow[i-393216];
    u32 lo = (u32)f2bf(f4.x) | ((u32)f2bf(f4.y)<<16);
    u32 hi = (u32)f2bf(f4.z) | ((u32)f2bf(f4.w)<<16);
    u16* dst = (i < 393216) ? (wqkv + i) : (owb + (i-393216));
    *(u32*)dst = lo;
    *(u32*)(dst+2) = hi;
    return;
  }
  nws[tid] = nw[tid];
  const int b = blk>>6, n0 = (blk&63)*64;
  const int cq = tid>>6, px = tid&63;
  const float* xp = x + (size_t)b*(C_*N_) + (size_t)(cq*64)*N_ + n0 + px;
  float v[64]; float s = 0.f;
  #pragma unroll
  for (int i=0;i<64;i++){ float t = xp[(size_t)i*N_]; v[i]=t; s = fmaf(t,t,s); }
  red[tid] = s;
  __syncthreads();
  const float st = red[px] + red[64+px] + red[128+px] + red[192+px];
  const float r = 16.0f / fmaxf(sqrtf(st), 1e-12f);
  u16* o = xnT + ((size_t)b*4096 + n0 + px)*256 + cq*64;
  #pragma unroll
  for (int i=0;i<64;i+=2){
    *(u32*)(o+i) = (u32)f2bf(v[i]*r*nws[cq*64+i]) | ((u32)f2bf(v[i+1]*r*nws[cq*64+i+1])<<16);
  }
}

// ---------------- kernel B: LDS-staged K/V GEMM + fixed-M softmax (ch=4, R21 proven) -----
__global__ __launch_bounds__(256,3) void k_kv(const u16* __restrict__ xnT, const u16* __restrict__ wqkv,
    u16* __restrict__ ctxp, float* __restrict__ Mp, float* __restrict__ Sp){
  __shared__ u16 xs[64*256];     // 32KB staged x tile (swizzled)
  __shared__ u16 pbuf[64*72];
  __shared__ u16 vbuf[64*72];
  const int idx = blockIdx.x;
  const int ch = idx&3, h = (idx>>2)&7, b = idx>>5;
  const int tid=threadIdx.x, w=tid>>6, l=tid&63, l15=l&15, lg=l>>4;
  const int swl = (l15&7)<<4;
  const u16* xb  = xnT + (size_t)b*(4096*256);
  const int srow = (l>>5);
  const int scolB = (l&31)*16;
  s8v ak[8], av[8];
  {
    const u16* wkp = wqkv + (size_t)(512 + h*64 + w*16 + l15)*256 + lg*8;
    #pragma unroll
    for (int cs=0; cs<8; cs++){ ak[cs] = *(const s8v*)(wkp + cs*32); av[cs] = *(const s8v*)(wkp + 131072 + cs*32); }
  }
  int colOff[8];
  #pragma unroll
  for (int cs=0; cs<8; cs++) colOff[cs] = (((cs<<6)+(lg<<4)) ^ swl)>>1;

  f4v acc[4];
  #pragma unroll
  for (int et=0;et<4;et++) acc[et] = (f4v){0.f,0.f,0.f,0.f};
  float ps[4] = {0.f,0.f,0.f,0.f};

  {
    const int n0 = ch*1024;
    #pragma unroll
    for (int i=0;i<8;i++){
      int rloc = w*16 + i*2 + srow;
      int scol = scolB ^ ((rloc&7)<<4);
      gl_lds16(xb + (size_t)(n0+rloc)*256 + (scol>>1), &xs[(w*16+i*2)*256]);
    }
  }

  for (int t=0; t<16; ++t){
    __syncthreads();
    f4v kacc[4], vacc[4];
    #pragma unroll
    for (int ns=0;ns<4;ns++){ kacc[ns]=(f4v){0.f,0.f,0.f,0.f}; vacc[ns]=(f4v){0.f,0.f,0.f,0.f}; }
    #pragma unroll
    for (int cs=0; cs<8; cs++){
      #pragma unroll
      for (int ns=0; ns<4; ns++){
        s8v bfr = *(const s8v*)&xs[(ns*16+l15)*256 + colOff[cs]];
        kacc[ns] = MFMA16(ak[cs], bfr, kacc[ns], 0,0,0);
        vacc[ns] = MFMA16(av[cs], bfr, vacc[ns], 0,0,0);
      }
    }
    #pragma unroll
    for (int j=0;j<4;j++){
      const int row = w*16 + lg*4 + j;
      #pragma unroll
      for (int ns=0;ns<4;ns++){
        float e = __expf(kacc[ns][j] - 30.0f);
        ps[j] += e;
        pbuf[row*72 + ns*16+l15] = f2bf(e);
        vbuf[row*72 + ns*16+l15] = f2bf(vacc[ns][j]);
      }
    }
    __syncthreads();
    if (t<15){
      const int n0 = ch*1024 + (t+1)*64;
      #pragma unroll
      for (int i=0;i<8;i++){
        int rloc = w*16 + i*2 + srow;
        int scol = scolB ^ ((rloc&7)<<4);
        gl_lds16(xb + (size_t)(n0+rloc)*256 + (scol>>1), &xs[(w*16+i*2)*256]);
      }
    }
    #pragma unroll
    for (int ks=0; ks<2; ks++){
      s8v af = *(const s8v*)(pbuf + (w*16+l15)*72 + ks*32 + lg*8);
      #pragma unroll
      for (int et=0; et<4; et++){
        s8v bv = *(const s8v*)(vbuf + (et*16+l15)*72 + ks*32 + lg*8);
        acc[et] = MFMA16(af, bv, acc[et], 0,0,0);
      }
    }
  }
  u16* cp = ctxp + (((size_t)ch*16 + b)*8 + h)*4096;
  #pragma unroll
  for (int et=0; et<4; et++)
    #pragma unroll
    for (int j=0;j<4;j++)
      cp[(w*16+lg*4+j)*64 + et*16+l15] = f2bf(acc[et][j]);
  #pragma unroll
  for (int j=0;j<4;j++){
    float s = ps[j];
    s += __shfl_xor(s,1); s += __shfl_xor(s,2);
    s += __shfl_xor(s,4); s += __shfl_xor(s,8);
    ps[j] = s;
  }
  if (l15==0){
    #pragma unroll
    for (int j=0;j<4;j++){
      int rg = (b*8+h)*64 + w*16 + lg*4 + j;
      Mp[ch*8192+rg]=30.0f; Sp[ch*8192+rg]=ps[j];
    }
  }
}

// ---------------- kernel C: fused combine (4 chunks) + G = OW.ctx^T ----------------------
__global__ __launch_bounds__(256) void k_cg(const u16* __restrict__ ctxp, const float* __restrict__ Mp,
    const float* __restrict__ Sp, const u16* __restrict__ owb, u16* __restrict__ G){
  __shared__ u16 ctxs[64*72];
  __shared__ float fs[4][64];
  __shared__ float iSs[64];
  const int bh = blockIdx.x, h = bh&7, tid = threadIdx.x;   // 128 blocks
  const int w = tid>>6, l = tid&63, l15 = l&15, lg = l>>4;
  if (tid < 64){
    float m[4];
    float Mg = -1e30f;
    #pragma unroll
    for (int ch=0;ch<4;ch++){ m[ch] = Mp[ch*8192 + bh*64 + tid]; Mg = fmaxf(Mg, m[ch]); }
    float Sg = 0.f;
    #pragma unroll
    for (int ch=0;ch<4;ch++){
      float fv = __expf(m[ch]-Mg);
      fs[ch][tid] = fv;
      Sg += Sp[ch*8192 + bh*64 + tid]*fv;
    }
    iSs[tid] = 1.0f / Sg;
  }
  __syncthreads();
  {
    const int d = tid>>2, e0 = (tid&3)*16;
    const float fsc = iSs[d];
    #pragma unroll
    for (int i=0;i<16;i++){
      float v = 0.f;
      #pragma unroll
      for (int ch=0;ch<4;ch++)
        v += bf2f(ctxp[(size_t)ch*524288 + (size_t)bh*4096 + d*64 + e0+i]) * fs[ch][d];
      ctxs[d*72 + e0+i] = f2bf(v * fsc);
    }
  }
  s8v a[4][2];
  #pragma unroll
  for (int mt=0; mt<4; mt++)
    #pragma unroll
    for (int ks=0; ks<2; ks++)
      a[mt][ks] = *(const s8v*)(owb + (size_t)(w*64+mt*16+l15)*512 + h*64 + ks*32 + lg*8);
  __syncthreads();
  s8v bD[4][2];
  #pragma unroll
  for (int dt=0; dt<4; dt++)
    #pragma unroll
    for (int ks=0; ks<2; ks++)
      bD[dt][ks] = *(const s8v*)&ctxs[(dt*16+l15)*72 + ks*32 + lg*8];
  f4v acc[4][4];
  #pragma unroll
  for (int mt=0;mt<4;mt++)
    #pragma unroll
    for (int dt=0;dt<4;dt++) acc[mt][dt] = (f4v){0.f,0.f,0.f,0.f};
  #pragma unroll
  for (int ks=0; ks<2; ks++)
    #pragma unroll
    for (int mt=0; mt<4; mt++)
      #pragma unroll
      for (int dt=0; dt<4; dt++)
        acc[mt][dt] = MFMA16(a[mt][ks], bD[dt][ks], acc[mt][dt], 0,0,0);
  u16* gp = G + (size_t)bh*16384;
  #pragma unroll
  for (int mt=0; mt<4; mt++)
    #pragma unroll
    for (int dt=0; dt<4; dt++)
      #pragma unroll
      for (int j=0; j<4; j++)
        gp[(w*64 + mt*16 + lg*4 + j)*64 + dt*16 + l15] = f2bf(acc[mt][dt][j]);
}

// ---------------- kernel D: q-GEMM + fixed-M softmax + out-GEMM(G) + bias + RMS ----------
// R18 proven structure + XCD swizzle (R20).
__global__ __launch_bounds__(512,2) void k_qout(const u16* __restrict__ xnT, const u16* __restrict__ wqkv,
    const u16* __restrict__ Gg, const float* __restrict__ ob, const float* __restrict__ onw,
    float* __restrict__ out){
  __shared__ u16 WQb[2][64*256];   // 2x32KB, swizzle (row&15)<<4 bytes
  __shared__ u16 Gb[2][256*64];    // 2x32KB, swizzle (row&7)<<4 bytes
  __shared__ u16 qa[8][1024];      // per-wave [16 n][64 d], XOR (row&7)<<3 u16-units
  const int tid = threadIdx.x;
  const int w=tid>>6, l=tid&63, l15=l&15, lg=l>>4;
  const int raw = blockIdx.x;
  const int b = ((raw>>8)<<3) + (raw&7);   // half*8 + xcd
  const int t = (raw>>3)&31;
  const int n0 = t*128 + w*16;
  const u16* xb = xnT + ((size_t)b*4096 + n0)*256;
  const u16* Gbase = Gg + (size_t)b*8*16384;
  u16* qaw = qa[w];
  const int wqRow0 = (l>>5);             // + (i*8+w)*2
  const int wqColB = (l&31)*16;
  const int gRow0  = (l>>3);             // + (i*8+w)*8
  const int gColB  = (l&7)*16;
  s8v ax[8];
  #pragma unroll
  for (int cs=0;cs<8;cs++) ax[cs] = *(const s8v*)(xb + (size_t)l15*256 + cs*32 + lg*8);
  f4v oacc[16];
  #pragma unroll
  for (int mt=0;mt<16;mt++) oacc[mt] = (f4v){0.f,0.f,0.f,0.f};

  #pragma unroll
  for (int i=0;i<4;i++){
    int row = (i*8+w)*2 + wqRow0;
    int scol = wqColB ^ ((row&15)<<4);
    gl_lds16(wqkv + (size_t)row*256 + (scol>>1), &WQb[0][(i*8+w)*512]);
  }
  #pragma unroll
  for (int i=0;i<4;i++){
    int row = (i*8+w)*8 + gRow0;
    int scol = gColB ^ ((row&7)<<4);
    gl_lds16(Gbase + (size_t)row*64 + (scol>>1), &Gb[0][(i*8+w)*512]);
  }

  for (int h=0; h<8; ++h){
    const int p = h&1;
    __syncthreads();
    if (h<7){
      const u16* wqg = wqkv + (size_t)(h+1)*64*256;
      const u16* gg  = Gbase + (size_t)(h+1)*16384;
      #pragma unroll
      for (int i=0;i<4;i++){
        int row = (i*8+w)*2 + wqRow0;
        int scol = wqColB ^ ((row&15)<<4);
        gl_lds16(wqg + (size_t)row*256 + (scol>>1), &WQb[p^1][(i*8+w)*512]);
      }
      #pragma unroll
      for (int i=0;i<4;i++){
        int row = (i*8+w)*8 + gRow0;
        int scol = gColB ^ ((row&7)<<4);
        gl_lds16(gg + (size_t)row*64 + (scol>>1), &Gb[p^1][(i*8+w)*512]);
      }
    }
    f4v qacc[4];
    #pragma unroll
    for (int dt=0;dt<4;dt++) qacc[dt] = (f4v){0.f,0.f,0.f,0.f};
    #pragma unroll
    for (int dt=0; dt<4; dt++){
      #pragma unroll
      for (int cs=0; cs<8; cs++){
        s8v bw = *(const s8v*)&WQb[p][(dt*16+l15)*256 + ((((cs<<6)|(lg<<4)) ^ (l15<<4))>>1)];
        qacc[dt] = MFMA16(ax[cs], bw, qacc[dt], 0,0,0);
      }
    }
    #pragma unroll
    for (int j=0;j<4;j++){
      float e[4]; float s = 0.f;
      #pragma unroll
      for (int dt=0;dt<4;dt++){ e[dt] = __expf(qacc[dt][j]-30.0f); s += e[dt]; }
      s += __shfl_xor(s,1); s += __shfl_xor(s,2);
      s += __shfl_xor(s,4); s += __shfl_xor(s,8);
      const float inv = 0.125f/s;
      #pragma unroll
      for (int dt=0;dt<4;dt++){
        int row = lg*4+j;
        qaw[((row<<6) + dt*16 + l15) ^ ((row&7)<<3)] = f2bf(e[dt]*inv);
      }
    }
    #pragma unroll
    for (int ks=0; ks<2; ks++){
      s8v ba = *(const s8v*)&qaw[(l15<<6) + ((((ks<<6)|(lg<<4)) ^ ((l15&7)<<4))>>1)];
      #pragma unroll
      for (int mt=0; mt<16; mt++){
        s8v aw = *(const s8v*)&Gb[p][(mt*16+l15)*64 + ((((ks<<6)|(lg<<4)) ^ ((l15&7)<<4))>>1)];
        oacc[mt] = MFMA16(aw, ba, oacc[mt], 0,0,0);
      }
    }
  }
  float ss = 0.f;
  #pragma unroll
  for (int mt=0;mt<16;mt++){
    const float4 o4 = *(const float4*)&ob[mt*16 + lg*4];
    #pragma unroll
    for (int j=0;j<4;j++){
      float v = oacc[mt][j] + ((const float*)&o4)[j];
      oacc[mt][j] = v;
      ss = fmaf(v,v,ss);
    }
  }
  ss += __shfl_xor(ss, 16);
  ss += __shfl_xor(ss, 32);
  const float r = 16.0f / fmaxf(sqrtf(ss), 1e-12f);
  float* op = out + (size_t)b*(256*4096) + n0 + l15;
  #pragma unroll
  for (int mt=0;mt<16;mt++){
    const float4 w4 = *(const float4*)&onw[mt*16 + lg*4];
    #pragma unroll
    for (int j=0;j<4;j++){
      int cout = mt*16+lg*4+j;
      op[(size_t)cout*4096] = oacc[mt][j] * r * ((const float*)&w4)[j];
    }
  }
}

extern "C" void kernel_launch(void* const* d_in, const int* in_sizes, int n_in,
                              void* d_out, int out_size, void* d_ws, size_t ws_size,
                              hipStream_t stream){
  const float* x    = (const float*)d_in[0];
  const float* nw   = (const float*)d_in[1];
  const float* qkvw = (const float*)d_in[2];
  const float* ow   = (const float*)d_in[3];
  const float* ob   = (const float*)d_in[4];
  const float* onw  = (const float*)d_in[5];
  float* out = (float*)d_out;
  char* ws = (char*)d_ws;
  u16*   xnT  = (u16*)(ws);                    // 33,554,432 B
  u16*   wqkv = (u16*)(ws + 33554432);         //    786,432 B
  u16*   owb  = (u16*)(ws + 34340864);         //    262,144 B
  u16*   ctxp = (u16*)(ws + 35651584);         //  4,194,304 B (4 chunks bf16)
  float* Mp   = (float*)(ws + 44040192);       //    131,072 B
  float* Sp   = (float*)(ws + 44302336);       //    131,072 B
  u16*   Gsafe= (u16*)(ws + 44564480);         //  4,194,304 B (disjoint region)
  (void)in_sizes; (void)n_in; (void)out_size; (void)ws_size;

  k_prep <<<1536, 256, 0, stream>>>(x, nw, xnT, qkvw, ow, wqkv, owb);
  k_kv   <<<512, 256, 0, stream>>>(xnT, wqkv, ctxp, Mp, Sp);
  k_cg   <<<128, 256, 0, stream>>>(ctxp, Mp, Sp, owb, Gsafe);
  k_qout <<<512, 512, 0, stream>>>(xnT, wqkv, Gsafe, ob, onw, out);
}